// Round 7
// baseline (364.468 us; speedup 1.0000x reference)
//
#include <hip/hip_runtime.h>

typedef unsigned int u32;
typedef unsigned short u16;
typedef unsigned char u8;
typedef __attribute__((ext_vector_type(8))) short short8;
typedef __attribute__((ext_vector_type(4))) float f32x4;
typedef __attribute__((ext_vector_type(2))) float f32x2;

#define MAXBIN 1024  // bins of 128 dsts; N=100k -> 782 bins

__device__ inline float bfu2f(u32 u) { return __builtin_bit_cast(float, u); }
__device__ inline u16 f2bf(float f) {
    u32 u = __builtin_bit_cast(u32, f);
    u32 r = (u + 0x7fffu + ((u >> 16) & 1u)) >> 16;  // RTNE
    return (u16)r;
}

// ---------- CSR build: two-level binned counting sort, LDS-resident counters ----
__global__ __launch_bounds__(256) void k_bhist(const int* __restrict__ ei, int E, int W,
                                               int* __restrict__ binTot, int NBIN) {
    __shared__ int h[MAXBIN];
    int tid = threadIdx.x;
    for (int i = tid; i < NBIN; i += 256) h[i] = 0;
    __syncthreads();
    int s = blockIdx.x * W, e = min(E, s + W);
    for (int j = s + tid; j < e; j += 256) atomicAdd(&h[ei[E + j] >> 7], 1);
    __syncthreads();
    for (int i = tid; i < NBIN; i += 256) {
        int v = h[i];
        if (v) atomicAdd(&binTot[i], v);
    }
}

__global__ void k_bscan(const int* __restrict__ binTot, int NBIN,
                        int* __restrict__ binStart, int* __restrict__ binCur) {
    __shared__ int wsum[4];
    int t = threadIdx.x;
    int base = t * 4;
    int v0 = (base + 0 < NBIN) ? binTot[base + 0] : 0;
    int v1 = (base + 1 < NBIN) ? binTot[base + 1] : 0;
    int v2 = (base + 2 < NBIN) ? binTot[base + 2] : 0;
    int v3 = (base + 3 < NBIN) ? binTot[base + 3] : 0;
    int s = v0 + v1 + v2 + v3;
    int lane = t & 63, wv = t >> 6;
    int isc = s;
    for (int d = 1; d < 64; d <<= 1) { int o = __shfl_up(isc, d, 64); if (lane >= d) isc += o; }
    if (lane == 63) wsum[wv] = isc;
    __syncthreads();
    int woff = 0;
    for (int w = 0; w < wv; w++) woff += wsum[w];
    int run = woff + isc - s;
    if (base + 0 < NBIN) { binStart[base + 0] = run; binCur[base + 0] = run; } run += v0;
    if (base + 1 < NBIN) { binStart[base + 1] = run; binCur[base + 1] = run; } run += v1;
    if (base + 2 < NBIN) { binStart[base + 2] = run; binCur[base + 2] = run; } run += v2;
    if (base + 3 < NBIN) { binStart[base + 3] = run; binCur[base + 3] = run; }
    if (t == 255) binStart[NBIN] = wsum[0] + wsum[1] + wsum[2] + wsum[3];
}

__global__ __launch_bounds__(256) void k_bscatter(const int* __restrict__ ei, int E, int W,
                                                  int* __restrict__ binCur,
                                                  u32* __restrict__ binned, int NBIN) {
    __shared__ int lh[MAXBIN];
    __shared__ int lb[MAXBIN];
    int tid = threadIdx.x;
    for (int i = tid; i < NBIN; i += 256) lh[i] = 0;
    __syncthreads();
    int s = blockIdx.x * W, e = min(E, s + W);
    for (int j = s + tid; j < e; j += 256) atomicAdd(&lh[ei[E + j] >> 7], 1);
    __syncthreads();
    for (int i = tid; i < NBIN; i += 256) {
        int h = lh[i];
        lb[i] = h ? atomicAdd(&binCur[i], h) : 0;
    }
    __syncthreads();
    for (int i = tid; i < NBIN; i += 256) lh[i] = 0;
    __syncthreads();
    for (int j = s + tid; j < e; j += 256) {
        int d = ei[E + j];
        int b = d >> 7;
        int r = atomicAdd(&lh[b], 1);
        binned[lb[b] + r] = ((u32)ei[j] << 7) | (u32)(d & 127);
    }
}

__global__ __launch_bounds__(256) void k_bcsr(const u32* __restrict__ binned,
                                              const int* __restrict__ binStart,
                                              int N, int E, int* __restrict__ offs,
                                              float* __restrict__ dinv,
                                              int* __restrict__ csr, int NBIN) {
    __shared__ int cnt[128];
    __shared__ int off[128];
    __shared__ int tot;
    int b = blockIdx.x;
    int tid = threadIdx.x;
    int dLo = b << 7;
    int nd = min(128, N - dLo);
    int e0 = binStart[b], e1 = binStart[b + 1];
    if (tid < 128) cnt[tid] = 0;
    __syncthreads();
    for (int j = e0 + tid; j < e1; j += 256) atomicAdd(&cnt[binned[j] & 127u], 1);
    __syncthreads();
    int c = (tid < 128) ? cnt[tid] : 0;
    int lane = tid & 63;
    int isc = c;
    for (int d = 1; d < 64; d <<= 1) { int o = __shfl_up(isc, d, 64); if (lane >= d) isc += o; }
    if (tid == 63) tot = isc;
    __syncthreads();
    int add = (tid >= 64 && tid < 128) ? tot : 0;
    if (tid < 128) off[tid] = add + isc - c;
    __syncthreads();
    if (tid < nd) {
        offs[dLo + tid] = e0 + off[tid];
        dinv[dLo + tid] = rsqrtf((float)(c + 1));
    }
    if (b == NBIN - 1 && tid == 0) offs[N] = E;
    if (tid < 128) cnt[tid] = 0;
    __syncthreads();
    for (int j = e0 + tid; j < e1; j += 256) {
        u32 v = binned[j];
        int d7 = (int)(v & 127u);
        int r = atomicAdd(&cnt[d7], 1);
        csr[e0 + off[d7] + r] = (int)(v >> 7);
    }
}

// ---------- fused weight converts (W[K][M] row-major -> Wt[M][K] bf16) ----------
__global__ void k_wtall(const float* __restrict__ W1, const float* __restrict__ W2,
                        const float* __restrict__ W3, u16* __restrict__ wt1,
                        u16* __restrict__ wt2, u16* __restrict__ wt3) {
    int idx = blockIdx.x * 256 + threadIdx.x;
    if (idx < 16384) {
        int k = idx >> 7, m = idx & 127;
        wt1[m * 128 + k] = f2bf(W1[idx]);
    } else if (idx < 32768) {
        int i = idx - 16384, k = i >> 7, m = i & 127;
        wt2[m * 128 + k] = f2bf(W2[i]);
    } else if (idx < 40960) {
        int i = idx - 32768, k = i >> 6, m = i & 63;
        wt3[m * 128 + k] = f2bf(W3[i]);
    }
}

// ---------- GEMM: g = (x @ W) * dinv[row]; writes bf16 (self) + fp8x16 (gather) ----------
template <int M, bool F32IN>
__global__ __launch_bounds__(256) void k_gemm(const void* __restrict__ xin,
                                              const u16* __restrict__ wt,
                                              const float* __restrict__ dinv,
                                              u16* __restrict__ g16,
                                              u8* __restrict__ g8, int N) {
    constexpr int K = 128;
    constexpr int LDK = 136;
    __shared__ u16 lwt[M * LDK];
    int tid = threadIdx.x;
    const uint4* wsrc = (const uint4*)wt;
#pragma unroll
    for (int c = tid; c < M * K / 8; c += 256) {
        int row = c >> 4, kc = c & 15;
        *(uint4*)&lwt[row * LDK + kc * 8] = wsrc[c];
    }
    __syncthreads();
    int lane = tid & 63, wv = tid >> 6;
    int node = blockIdx.x * 64 + wv * 16 + (lane & 15);
    int nodec = min(node, N - 1);
    int kr = (lane >> 4) * 8;
    f32x4 acc[M / 16];
#pragma unroll
    for (int t = 0; t < M / 16; t++) acc[t] = (f32x4){0.f, 0.f, 0.f, 0.f};
#pragma unroll
    for (int ks = 0; ks < 4; ks++) {
        short8 bfr;
        if (F32IN) {
            const float* xr = (const float*)xin + (size_t)nodec * K + ks * 32 + kr;
            float4 fa = *(const float4*)xr;
            float4 fb = *(const float4*)(xr + 4);
            bfr = (short8){(short)f2bf(fa.x), (short)f2bf(fa.y), (short)f2bf(fa.z),
                           (short)f2bf(fa.w), (short)f2bf(fb.x), (short)f2bf(fb.y),
                           (short)f2bf(fb.z), (short)f2bf(fb.w)};
        } else {
            bfr = *(const short8*)((const u16*)xin + (size_t)nodec * K + ks * 32 + kr);
        }
#pragma unroll
        for (int t = 0; t < M / 16; t++) {
            short8 afr = *(const short8*)&lwt[(t * 16 + (lane & 15)) * LDK + ks * 32 + kr];
            acc[t] = __builtin_amdgcn_mfma_f32_16x16x32_bf16(afr, bfr, acc[t], 0, 0, 0);
        }
    }
    if (node < N) {
        float dv = dinv[node];
        float dv16 = dv * 16.0f;
        int r0 = (lane >> 4) * 4;
#pragma unroll
        for (int t = 0; t < M / 16; t++) {
            float v0 = acc[t][0] * dv, v1 = acc[t][1] * dv;
            float v2 = acc[t][2] * dv, v3 = acc[t][3] * dv;
            u32 lo = (u32)f2bf(v0) | ((u32)f2bf(v1) << 16);
            u32 hi = (u32)f2bf(v2) | ((u32)f2bf(v3) << 16);
            *(uint2*)&g16[(size_t)node * M + t * 16 + r0] = make_uint2(lo, hi);
            u32 w = __builtin_amdgcn_cvt_pk_fp8_f32(acc[t][0] * dv16, acc[t][1] * dv16, 0, false);
            w = __builtin_amdgcn_cvt_pk_fp8_f32(acc[t][2] * dv16, acc[t][3] * dv16, w, true);
            *(u32*)(g8 + (size_t)node * M + t * 16 + r0) = w;
        }
    }
}

// ---------- aggregation, quarter-wave edge-parallel, tail-split + packed adds ----
__global__ __launch_bounds__(256) void k_agg128(const u8* __restrict__ g8,
                                                const u16* __restrict__ g16,
                                                const int* __restrict__ offs,
                                                const int* __restrict__ csr,
                                                const float* __restrict__ dinv,
                                                const float* __restrict__ bias,
                                                u16* __restrict__ hout, int N) {
    int wid = (blockIdx.x * 256 + threadIdx.x) >> 6;  // one wave per node
    if (wid >= N) return;
    int lane = threadIdx.x & 63;
    int q = lane >> 4;
    int f = lane & 15;
    int s = offs[wid], e = offs[wid + 1];
    const u8* gf = g8 + f * 8;  // u32 row offsets -> saddr addressing
    f32x2 a01 = {0.f, 0.f}, a23 = {0.f, 0.f}, a45 = {0.f, 0.f}, a67 = {0.f, 0.f};
    int j = s;
    for (; j + 8 <= e; j += 8) {  // full groups: no masking
        int srcA = csr[j + q], srcB = csr[j + 4 + q];
        uint2 wA = *(const uint2*)(gf + ((u32)srcA << 7));
        uint2 wB = *(const uint2*)(gf + ((u32)srcB << 7));
        f32x2 p0 = __builtin_amdgcn_cvt_pk_f32_fp8((int)wA.x, false);
        f32x2 p1 = __builtin_amdgcn_cvt_pk_f32_fp8((int)wA.x, true);
        f32x2 p2 = __builtin_amdgcn_cvt_pk_f32_fp8((int)wA.y, false);
        f32x2 p3 = __builtin_amdgcn_cvt_pk_f32_fp8((int)wA.y, true);
        f32x2 r0 = __builtin_amdgcn_cvt_pk_f32_fp8((int)wB.x, false);
        f32x2 r1 = __builtin_amdgcn_cvt_pk_f32_fp8((int)wB.x, true);
        f32x2 r2 = __builtin_amdgcn_cvt_pk_f32_fp8((int)wB.y, false);
        f32x2 r3 = __builtin_amdgcn_cvt_pk_f32_fp8((int)wB.y, true);
        a01 += p0 + r0; a23 += p1 + r1; a45 += p2 + r2; a67 += p3 + r3;
    }
    if (j < e) {  // single masked tail
        int iA = j + q, iB = j + 4 + q;
        int srcA = csr[min(iA, e - 1)];
        int srcB = csr[min(iB, e - 1)];
        uint2 wA = *(const uint2*)(gf + ((u32)srcA << 7));
        uint2 wB = *(const uint2*)(gf + ((u32)srcB << 7));
        if (iA >= e) { wA.x = 0u; wA.y = 0u; }
        if (iB >= e) { wB.x = 0u; wB.y = 0u; }
        f32x2 p0 = __builtin_amdgcn_cvt_pk_f32_fp8((int)wA.x, false);
        f32x2 p1 = __builtin_amdgcn_cvt_pk_f32_fp8((int)wA.x, true);
        f32x2 p2 = __builtin_amdgcn_cvt_pk_f32_fp8((int)wA.y, false);
        f32x2 p3 = __builtin_amdgcn_cvt_pk_f32_fp8((int)wA.y, true);
        f32x2 r0 = __builtin_amdgcn_cvt_pk_f32_fp8((int)wB.x, false);
        f32x2 r1 = __builtin_amdgcn_cvt_pk_f32_fp8((int)wB.x, true);
        f32x2 r2 = __builtin_amdgcn_cvt_pk_f32_fp8((int)wB.y, false);
        f32x2 r3 = __builtin_amdgcn_cvt_pk_f32_fp8((int)wB.y, true);
        a01 += p0 + r0; a23 += p1 + r1; a45 += p2 + r2; a67 += p3 + r3;
    }
    float a[8] = {a01.x, a01.y, a23.x, a23.y, a45.x, a45.y, a67.x, a67.y};
#pragma unroll
    for (int i = 0; i < 8; i++) {
        a[i] += __shfl_xor(a[i], 16, 64);
        a[i] += __shfl_xor(a[i], 32, 64);
    }
    if (lane < 16) {
        float dv = dinv[wid];
        float sc = dv * 0.0625f;
        uint4 sp = *(const uint4*)(g16 + (size_t)wid * 128 + f * 8);
        float4 b0 = *(const float4*)(bias + f * 8);
        float4 b1 = *(const float4*)(bias + f * 8 + 4);
        float sv[8] = {bfu2f(sp.x << 16), bfu2f(sp.x & 0xffff0000u),
                       bfu2f(sp.y << 16), bfu2f(sp.y & 0xffff0000u),
                       bfu2f(sp.z << 16), bfu2f(sp.z & 0xffff0000u),
                       bfu2f(sp.w << 16), bfu2f(sp.w & 0xffff0000u)};
        float bv[8] = {b0.x, b0.y, b0.z, b0.w, b1.x, b1.y, b1.z, b1.w};
        u32 o[4];
#pragma unroll
        for (int i = 0; i < 4; i++) {
            float v0 = fmaxf(fmaf(a[2 * i], sc, fmaf(sv[2 * i], dv, bv[2 * i])), 0.f);
            float v1 = fmaxf(fmaf(a[2 * i + 1], sc, fmaf(sv[2 * i + 1], dv, bv[2 * i + 1])), 0.f);
            o[i] = (u32)f2bf(v0) | ((u32)f2bf(v1) << 16);
        }
        *(uint4*)&hout[(size_t)wid * 128 + f * 8] = make_uint4(o[0], o[1], o[2], o[3]);
    }
}

// ---------- layer-3 aggregation + log_softmax (F=64, fp32 out) ----------
__global__ __launch_bounds__(256) void k_agg64(const u8* __restrict__ g8,
                                               const u16* __restrict__ g16,
                                               const int* __restrict__ offs,
                                               const int* __restrict__ csr,
                                               const float* __restrict__ dinv,
                                               const float* __restrict__ bias,
                                               float* __restrict__ out, int N) {
    int wid = (blockIdx.x * 256 + threadIdx.x) >> 6;
    if (wid >= N) return;
    int lane = threadIdx.x & 63;
    int q = lane >> 4;
    int f = lane & 15;
    int s = offs[wid], e = offs[wid + 1];
    const u8* gf = g8 + f * 4;
    f32x2 a01 = {0.f, 0.f}, a23 = {0.f, 0.f};
    int j = s;
    for (; j + 8 <= e; j += 8) {
        int srcA = csr[j + q], srcB = csr[j + 4 + q];
        u32 wA = *(const u32*)(gf + ((u32)srcA << 6));
        u32 wB = *(const u32*)(gf + ((u32)srcB << 6));
        f32x2 p0 = __builtin_amdgcn_cvt_pk_f32_fp8((int)wA, false);
        f32x2 p1 = __builtin_amdgcn_cvt_pk_f32_fp8((int)wA, true);
        f32x2 r0 = __builtin_amdgcn_cvt_pk_f32_fp8((int)wB, false);
        f32x2 r1 = __builtin_amdgcn_cvt_pk_f32_fp8((int)wB, true);
        a01 += p0 + r0; a23 += p1 + r1;
    }
    if (j < e) {
        int iA = j + q, iB = j + 4 + q;
        int srcA = csr[min(iA, e - 1)];
        int srcB = csr[min(iB, e - 1)];
        u32 wA = *(const u32*)(gf + ((u32)srcA << 6));
        u32 wB = *(const u32*)(gf + ((u32)srcB << 6));
        if (iA >= e) wA = 0u;
        if (iB >= e) wB = 0u;
        f32x2 p0 = __builtin_amdgcn_cvt_pk_f32_fp8((int)wA, false);
        f32x2 p1 = __builtin_amdgcn_cvt_pk_f32_fp8((int)wA, true);
        f32x2 r0 = __builtin_amdgcn_cvt_pk_f32_fp8((int)wB, false);
        f32x2 r1 = __builtin_amdgcn_cvt_pk_f32_fp8((int)wB, true);
        a01 += p0 + r0; a23 += p1 + r1;
    }
    float a[4] = {a01.x, a01.y, a23.x, a23.y};
#pragma unroll
    for (int i = 0; i < 4; i++) {
        a[i] += __shfl_xor(a[i], 16, 64);
        a[i] += __shfl_xor(a[i], 32, 64);
    }
    if (lane < 16) {
        float dv = dinv[wid];
        float sc = dv * 0.0625f;
        uint2 sp = *(const uint2*)(g16 + (size_t)wid * 64 + f * 4);
        float4 bb = *(const float4*)(bias + f * 4);
        float v0 = fmaf(a[0], sc, fmaf(bfu2f(sp.x << 16), dv, bb.x));
        float v1 = fmaf(a[1], sc, fmaf(bfu2f(sp.x & 0xffff0000u), dv, bb.y));
        float v2 = fmaf(a[2], sc, fmaf(bfu2f(sp.y << 16), dv, bb.z));
        float v3 = fmaf(a[3], sc, fmaf(bfu2f(sp.y & 0xffff0000u), dv, bb.w));
        float m = fmaxf(fmaxf(v0, v1), fmaxf(v2, v3));
#pragma unroll
        for (int d = 8; d >= 1; d >>= 1) m = fmaxf(m, __shfl_xor(m, d, 64));
        float ssum = __expf(v0 - m) + __expf(v1 - m) + __expf(v2 - m) + __expf(v3 - m);
#pragma unroll
        for (int d = 8; d >= 1; d >>= 1) ssum += __shfl_xor(ssum, d, 64);
        float lg = m + __logf(ssum);
        *(float4*)&out[(size_t)wid * 64 + f * 4] =
            make_float4(v0 - lg, v1 - lg, v2 - lg, v3 - lg);
    }
}

extern "C" void kernel_launch(void* const* d_in, const int* in_sizes, int n_in,
                              void* d_out, int out_size, void* d_ws, size_t ws_size,
                              hipStream_t stream) {
    const float* x  = (const float*)d_in[0];
    const int*   ei = (const int*)d_in[1];
    const float* W1 = (const float*)d_in[2];
    const float* b1 = (const float*)d_in[3];
    const float* W2 = (const float*)d_in[4];
    const float* b2 = (const float*)d_in[5];
    const float* W3 = (const float*)d_in[6];
    const float* b3 = (const float*)d_in[7];
    const int N = in_sizes[0] / 128;
    const int E = in_sizes[1] / 2;
    const int NBIN = (N + 127) >> 7;  // bins of 128 dsts

    char* ws = (char*)d_ws;
    size_t o = 0;
    auto alloc = [&](size_t bytes) -> char* {
        char* p = ws + o;
        o += (bytes + 255) & ~(size_t)255;
        return p;
    };
    int*   binTot = (int*)alloc((size_t)MAXBIN * 4);
    int*   binSt  = (int*)alloc((size_t)(MAXBIN + 1) * 4);
    int*   binCur = (int*)alloc((size_t)MAXBIN * 4);
    float* dinv   = (float*)alloc((size_t)N * 4);
    int*   offs   = (int*)alloc((size_t)(N + 1) * 4);
    int*   csr    = (int*)alloc((size_t)E * 4);
    u16*   wt1    = (u16*)alloc(128 * 128 * 2);
    u16*   wt2    = (u16*)alloc(128 * 128 * 2);
    u16*   wt3    = (u16*)alloc(64 * 128 * 2);
    u16*   g16    = (u16*)alloc((size_t)N * 128 * 2);
    u8*    g8     = (u8*)alloc((size_t)N * 128);
    u16*   hbuf   = (u16*)alloc((size_t)N * 128 * 2);
    u32*   binned = (u32*)g16;  // lifetime-disjoint alias: dead before first GEMM
    float* outp   = (float*)d_out;

    hipMemsetAsync(binTot, 0, (size_t)MAXBIN * 4, stream);
    int W = (E + 255) / 256;  // edge chunk per block for 256-block passes
    k_bhist<<<256, 256, 0, stream>>>(ei, E, W, binTot, NBIN);
    k_bscan<<<1, 256, 0, stream>>>(binTot, NBIN, binSt, binCur);
    k_bscatter<<<256, 256, 0, stream>>>(ei, E, W, binCur, binned, NBIN);
    k_bcsr<<<NBIN, 256, 0, stream>>>(binned, binSt, N, E, offs, dinv, csr, NBIN);
    k_wtall<<<(40960 + 255) / 256, 256, 0, stream>>>(W1, W2, W3, wt1, wt2, wt3);

    int gG = (N + 63) / 64;                       // GEMM: 64 nodes/block
    int gA = (int)(((size_t)N * 64 + 255) / 256); // agg: 1 wave/node

    k_gemm<128, true ><<<gG, 256, 0, stream>>>(x,    wt1, dinv, g16, g8, N);
    k_agg128<<<gA, 256, 0, stream>>>(g8, g16, offs, csr, dinv, b1, hbuf, N);
    k_gemm<128, false><<<gG, 256, 0, stream>>>(hbuf, wt2, dinv, g16, g8, N);
    k_agg128<<<gA, 256, 0, stream>>>(g8, g16, offs, csr, dinv, b2, hbuf, N);
    k_gemm<64,  false><<<gG, 256, 0, stream>>>(hbuf, wt3, dinv, g16, g8, N);
    k_agg64<<<gA, 256, 0, stream>>>(g8, g16, offs, csr, dinv, b3, outp, N);
}

// Round 8
// 358.604 us; speedup vs baseline: 1.0164x; 1.0164x over previous
//
#include <hip/hip_runtime.h>

typedef unsigned int u32;
typedef unsigned short u16;
typedef unsigned char u8;
typedef __attribute__((ext_vector_type(8))) short short8;
typedef __attribute__((ext_vector_type(4))) float f32x4;
typedef __attribute__((ext_vector_type(2))) float f32x2;

#define MAXBIN 1024  // bins of 128 dsts; N=100k -> 782 bins

__device__ inline float bfu2f(u32 u) { return __builtin_bit_cast(float, u); }
__device__ inline u16 f2bf(float f) {
    u32 u = __builtin_bit_cast(u32, f);
    u32 r = (u + 0x7fffu + ((u >> 16) & 1u)) >> 16;  // RTNE
    return (u16)r;
}

// ---------- CSR build: two-level binned counting sort, LDS-resident counters ----
__global__ __launch_bounds__(256) void k_bhist(const int* __restrict__ ei, int E, int W,
                                               int* __restrict__ binTot, int NBIN) {
    __shared__ int h[MAXBIN];
    int tid = threadIdx.x;
    for (int i = tid; i < NBIN; i += 256) h[i] = 0;
    __syncthreads();
    int s = blockIdx.x * W, e = min(E, s + W);
    for (int j = s + tid; j < e; j += 256) atomicAdd(&h[ei[E + j] >> 7], 1);
    __syncthreads();
    for (int i = tid; i < NBIN; i += 256) {
        int v = h[i];
        if (v) atomicAdd(&binTot[i], v);
    }
}

__global__ void k_bscan(const int* __restrict__ binTot, int NBIN,
                        int* __restrict__ binStart, int* __restrict__ binCur) {
    __shared__ int wsum[4];
    int t = threadIdx.x;
    int base = t * 4;
    int v0 = (base + 0 < NBIN) ? binTot[base + 0] : 0;
    int v1 = (base + 1 < NBIN) ? binTot[base + 1] : 0;
    int v2 = (base + 2 < NBIN) ? binTot[base + 2] : 0;
    int v3 = (base + 3 < NBIN) ? binTot[base + 3] : 0;
    int s = v0 + v1 + v2 + v3;
    int lane = t & 63, wv = t >> 6;
    int isc = s;
    for (int d = 1; d < 64; d <<= 1) { int o = __shfl_up(isc, d, 64); if (lane >= d) isc += o; }
    if (lane == 63) wsum[wv] = isc;
    __syncthreads();
    int woff = 0;
    for (int w = 0; w < wv; w++) woff += wsum[w];
    int run = woff + isc - s;
    if (base + 0 < NBIN) { binStart[base + 0] = run; binCur[base + 0] = run; } run += v0;
    if (base + 1 < NBIN) { binStart[base + 1] = run; binCur[base + 1] = run; } run += v1;
    if (base + 2 < NBIN) { binStart[base + 2] = run; binCur[base + 2] = run; } run += v2;
    if (base + 3 < NBIN) { binStart[base + 3] = run; binCur[base + 3] = run; }
    if (t == 255) binStart[NBIN] = wsum[0] + wsum[1] + wsum[2] + wsum[3];
}

__global__ __launch_bounds__(256) void k_bscatter(const int* __restrict__ ei, int E, int W,
                                                  int* __restrict__ binCur,
                                                  u32* __restrict__ binned, int NBIN) {
    __shared__ int lh[MAXBIN];
    __shared__ int lb[MAXBIN];
    int tid = threadIdx.x;
    for (int i = tid; i < NBIN; i += 256) lh[i] = 0;
    __syncthreads();
    int s = blockIdx.x * W, e = min(E, s + W);
    for (int j = s + tid; j < e; j += 256) atomicAdd(&lh[ei[E + j] >> 7], 1);
    __syncthreads();
    for (int i = tid; i < NBIN; i += 256) {
        int h = lh[i];
        lb[i] = h ? atomicAdd(&binCur[i], h) : 0;
    }
    __syncthreads();
    for (int i = tid; i < NBIN; i += 256) lh[i] = 0;
    __syncthreads();
    for (int j = s + tid; j < e; j += 256) {
        int d = ei[E + j];
        int b = d >> 7;
        int r = atomicAdd(&lh[b], 1);
        binned[lb[b] + r] = ((u32)ei[j] << 7) | (u32)(d & 127);
    }
}

__global__ __launch_bounds__(256) void k_bcsr(const u32* __restrict__ binned,
                                              const int* __restrict__ binStart,
                                              int N, int E, int* __restrict__ offs,
                                              float* __restrict__ dinv,
                                              int* __restrict__ csr, int NBIN) {
    __shared__ int cnt[128];
    __shared__ int off[128];
    __shared__ int tot;
    int b = blockIdx.x;
    int tid = threadIdx.x;
    int dLo = b << 7;
    int nd = min(128, N - dLo);
    int e0 = binStart[b], e1 = binStart[b + 1];
    if (tid < 128) cnt[tid] = 0;
    __syncthreads();
    for (int j = e0 + tid; j < e1; j += 256) atomicAdd(&cnt[binned[j] & 127u], 1);
    __syncthreads();
    int c = (tid < 128) ? cnt[tid] : 0;
    int lane = tid & 63;
    int isc = c;
    for (int d = 1; d < 64; d <<= 1) { int o = __shfl_up(isc, d, 64); if (lane >= d) isc += o; }
    if (tid == 63) tot = isc;
    __syncthreads();
    int add = (tid >= 64 && tid < 128) ? tot : 0;
    if (tid < 128) off[tid] = add + isc - c;
    __syncthreads();
    if (tid < nd) {
        offs[dLo + tid] = e0 + off[tid];
        dinv[dLo + tid] = rsqrtf((float)(c + 1));
    }
    if (b == NBIN - 1 && tid == 0) offs[N] = E;
    if (tid < 128) cnt[tid] = 0;
    __syncthreads();
    for (int j = e0 + tid; j < e1; j += 256) {
        u32 v = binned[j];
        int d7 = (int)(v & 127u);
        int r = atomicAdd(&cnt[d7], 1);
        csr[e0 + off[d7] + r] = (int)(v >> 7);
    }
}

// ---------- fused weight converts (W[K][M] row-major -> Wt[M][K] bf16) ----------
__global__ void k_wtall(const float* __restrict__ W1, const float* __restrict__ W2,
                        const float* __restrict__ W3, u16* __restrict__ wt1,
                        u16* __restrict__ wt2, u16* __restrict__ wt3) {
    int idx = blockIdx.x * 256 + threadIdx.x;
    if (idx < 16384) {
        int k = idx >> 7, m = idx & 127;
        wt1[m * 128 + k] = f2bf(W1[idx]);
    } else if (idx < 32768) {
        int i = idx - 16384, k = i >> 7, m = i & 127;
        wt2[m * 128 + k] = f2bf(W2[i]);
    } else if (idx < 40960) {
        int i = idx - 32768, k = i >> 6, m = i & 63;
        wt3[m * 128 + k] = f2bf(W3[i]);
    }
}

// ---------- GEMM: g = (x @ W) * dinv[row]; writes bf16 (self) + fp8x16 (gather) ----------
template <int M, bool F32IN>
__global__ __launch_bounds__(256) void k_gemm(const void* __restrict__ xin,
                                              const u16* __restrict__ wt,
                                              const float* __restrict__ dinv,
                                              u16* __restrict__ g16,
                                              u8* __restrict__ g8, int N) {
    constexpr int K = 128;
    constexpr int LDK = 136;
    __shared__ u16 lwt[M * LDK];
    int tid = threadIdx.x;
    const uint4* wsrc = (const uint4*)wt;
#pragma unroll
    for (int c = tid; c < M * K / 8; c += 256) {
        int row = c >> 4, kc = c & 15;
        *(uint4*)&lwt[row * LDK + kc * 8] = wsrc[c];
    }
    __syncthreads();
    int lane = tid & 63, wv = tid >> 6;
    int node = blockIdx.x * 64 + wv * 16 + (lane & 15);
    int nodec = min(node, N - 1);
    int kr = (lane >> 4) * 8;
    f32x4 acc[M / 16];
#pragma unroll
    for (int t = 0; t < M / 16; t++) acc[t] = (f32x4){0.f, 0.f, 0.f, 0.f};
#pragma unroll
    for (int ks = 0; ks < 4; ks++) {
        short8 bfr;
        if (F32IN) {
            const float* xr = (const float*)xin + (size_t)nodec * K + ks * 32 + kr;
            float4 fa = *(const float4*)xr;
            float4 fb = *(const float4*)(xr + 4);
            bfr = (short8){(short)f2bf(fa.x), (short)f2bf(fa.y), (short)f2bf(fa.z),
                           (short)f2bf(fa.w), (short)f2bf(fb.x), (short)f2bf(fb.y),
                           (short)f2bf(fb.z), (short)f2bf(fb.w)};
        } else {
            bfr = *(const short8*)((const u16*)xin + (size_t)nodec * K + ks * 32 + kr);
        }
#pragma unroll
        for (int t = 0; t < M / 16; t++) {
            short8 afr = *(const short8*)&lwt[(t * 16 + (lane & 15)) * LDK + ks * 32 + kr];
            acc[t] = __builtin_amdgcn_mfma_f32_16x16x32_bf16(afr, bfr, acc[t], 0, 0, 0);
        }
    }
    if (node < N) {
        float dv = dinv[node];
        float dv16 = dv * 16.0f;
        int r0 = (lane >> 4) * 4;
#pragma unroll
        for (int t = 0; t < M / 16; t++) {
            float v0 = acc[t][0] * dv, v1 = acc[t][1] * dv;
            float v2 = acc[t][2] * dv, v3 = acc[t][3] * dv;
            u32 lo = (u32)f2bf(v0) | ((u32)f2bf(v1) << 16);
            u32 hi = (u32)f2bf(v2) | ((u32)f2bf(v3) << 16);
            *(uint2*)&g16[(size_t)node * M + t * 16 + r0] = make_uint2(lo, hi);
            u32 w = __builtin_amdgcn_cvt_pk_fp8_f32(acc[t][0] * dv16, acc[t][1] * dv16, 0, false);
            w = __builtin_amdgcn_cvt_pk_fp8_f32(acc[t][2] * dv16, acc[t][3] * dv16, w, true);
            *(u32*)(g8 + (size_t)node * M + t * 16 + r0) = w;
        }
    }
}

// ---------- aggregation: 16 edges/iter, 4 gathers in flight, fully masked ----------
// quarter q handles edges j+4q..j+4q+3; lane covers 8 features via uint2 fp8.
__global__ __launch_bounds__(256) void k_agg128(const u8* __restrict__ g8,
                                                const u16* __restrict__ g16,
                                                const int* __restrict__ offs,
                                                const int* __restrict__ csr,
                                                const float* __restrict__ dinv,
                                                const float* __restrict__ bias,
                                                u16* __restrict__ hout, int N) {
    int wid = (blockIdx.x * 256 + threadIdx.x) >> 6;  // one wave per node
    if (wid >= N) return;
    int lane = threadIdx.x & 63;
    int q = lane >> 4;
    int f = lane & 15;
    int s = offs[wid], e = offs[wid + 1];
    const u8* gf = g8 + f * 8;  // u32 row offsets -> saddr addressing
    f32x2 a01 = {0.f, 0.f}, a23 = {0.f, 0.f}, a45 = {0.f, 0.f}, a67 = {0.f, 0.f};
    int em1 = e - 1;
    for (int j = s; j < e; j += 16) {
        int b4 = j + q * 4;
        int i1 = b4 + 1, i2 = b4 + 2, i3 = b4 + 3;
        int s0 = csr[min(b4, em1)];
        int s1 = csr[min(i1, em1)];
        int s2 = csr[min(i2, em1)];
        int s3 = csr[min(i3, em1)];
        uint2 w0 = *(const uint2*)(gf + ((u32)s0 << 7));
        uint2 w1 = *(const uint2*)(gf + ((u32)s1 << 7));
        uint2 w2 = *(const uint2*)(gf + ((u32)s2 << 7));
        uint2 w3 = *(const uint2*)(gf + ((u32)s3 << 7));
        if (b4 >= e) { w0.x = 0u; w0.y = 0u; }  // fp8 0x00 == 0.0
        if (i1 >= e) { w1.x = 0u; w1.y = 0u; }
        if (i2 >= e) { w2.x = 0u; w2.y = 0u; }
        if (i3 >= e) { w3.x = 0u; w3.y = 0u; }
        f32x2 t0, t1;
        t0 = __builtin_amdgcn_cvt_pk_f32_fp8((int)w0.x, false) +
             __builtin_amdgcn_cvt_pk_f32_fp8((int)w1.x, false);
        t1 = __builtin_amdgcn_cvt_pk_f32_fp8((int)w2.x, false) +
             __builtin_amdgcn_cvt_pk_f32_fp8((int)w3.x, false);
        a01 += t0 + t1;
        t0 = __builtin_amdgcn_cvt_pk_f32_fp8((int)w0.x, true) +
             __builtin_amdgcn_cvt_pk_f32_fp8((int)w1.x, true);
        t1 = __builtin_amdgcn_cvt_pk_f32_fp8((int)w2.x, true) +
             __builtin_amdgcn_cvt_pk_f32_fp8((int)w3.x, true);
        a23 += t0 + t1;
        t0 = __builtin_amdgcn_cvt_pk_f32_fp8((int)w0.y, false) +
             __builtin_amdgcn_cvt_pk_f32_fp8((int)w1.y, false);
        t1 = __builtin_amdgcn_cvt_pk_f32_fp8((int)w2.y, false) +
             __builtin_amdgcn_cvt_pk_f32_fp8((int)w3.y, false);
        a45 += t0 + t1;
        t0 = __builtin_amdgcn_cvt_pk_f32_fp8((int)w0.y, true) +
             __builtin_amdgcn_cvt_pk_f32_fp8((int)w1.y, true);
        t1 = __builtin_amdgcn_cvt_pk_f32_fp8((int)w2.y, true) +
             __builtin_amdgcn_cvt_pk_f32_fp8((int)w3.y, true);
        a67 += t0 + t1;
    }
    float a[8] = {a01.x, a01.y, a23.x, a23.y, a45.x, a45.y, a67.x, a67.y};
#pragma unroll
    for (int i = 0; i < 8; i++) {
        a[i] += __shfl_xor(a[i], 16, 64);
        a[i] += __shfl_xor(a[i], 32, 64);
    }
    if (lane < 16) {
        float dv = dinv[wid];
        float sc = dv * 0.0625f;
        uint4 sp = *(const uint4*)(g16 + (size_t)wid * 128 + f * 8);
        float4 b0 = *(const float4*)(bias + f * 8);
        float4 b1 = *(const float4*)(bias + f * 8 + 4);
        float sv[8] = {bfu2f(sp.x << 16), bfu2f(sp.x & 0xffff0000u),
                       bfu2f(sp.y << 16), bfu2f(sp.y & 0xffff0000u),
                       bfu2f(sp.z << 16), bfu2f(sp.z & 0xffff0000u),
                       bfu2f(sp.w << 16), bfu2f(sp.w & 0xffff0000u)};
        float bv[8] = {b0.x, b0.y, b0.z, b0.w, b1.x, b1.y, b1.z, b1.w};
        u32 o[4];
#pragma unroll
        for (int i = 0; i < 4; i++) {
            float v0 = fmaxf(fmaf(a[2 * i], sc, fmaf(sv[2 * i], dv, bv[2 * i])), 0.f);
            float v1 = fmaxf(fmaf(a[2 * i + 1], sc, fmaf(sv[2 * i + 1], dv, bv[2 * i + 1])), 0.f);
            o[i] = (u32)f2bf(v0) | ((u32)f2bf(v1) << 16);
        }
        *(uint4*)&hout[(size_t)wid * 128 + f * 8] = make_uint4(o[0], o[1], o[2], o[3]);
    }
}

// ---------- layer-3 aggregation + log_softmax (F=64, fp32 out) ----------
__global__ __launch_bounds__(256) void k_agg64(const u8* __restrict__ g8,
                                               const u16* __restrict__ g16,
                                               const int* __restrict__ offs,
                                               const int* __restrict__ csr,
                                               const float* __restrict__ dinv,
                                               const float* __restrict__ bias,
                                               float* __restrict__ out, int N) {
    int wid = (blockIdx.x * 256 + threadIdx.x) >> 6;
    if (wid >= N) return;
    int lane = threadIdx.x & 63;
    int q = lane >> 4;
    int f = lane & 15;
    int s = offs[wid], e = offs[wid + 1];
    const u8* gf = g8 + f * 4;
    f32x2 a01 = {0.f, 0.f}, a23 = {0.f, 0.f};
    int em1 = e - 1;
    for (int j = s; j < e; j += 16) {
        int b4 = j + q * 4;
        int i1 = b4 + 1, i2 = b4 + 2, i3 = b4 + 3;
        int s0 = csr[min(b4, em1)];
        int s1 = csr[min(i1, em1)];
        int s2 = csr[min(i2, em1)];
        int s3 = csr[min(i3, em1)];
        u32 w0 = *(const u32*)(gf + ((u32)s0 << 6));
        u32 w1 = *(const u32*)(gf + ((u32)s1 << 6));
        u32 w2 = *(const u32*)(gf + ((u32)s2 << 6));
        u32 w3 = *(const u32*)(gf + ((u32)s3 << 6));
        if (b4 >= e) w0 = 0u;
        if (i1 >= e) w1 = 0u;
        if (i2 >= e) w2 = 0u;
        if (i3 >= e) w3 = 0u;
        f32x2 t0 = __builtin_amdgcn_cvt_pk_f32_fp8((int)w0, false) +
                   __builtin_amdgcn_cvt_pk_f32_fp8((int)w1, false);
        f32x2 t1 = __builtin_amdgcn_cvt_pk_f32_fp8((int)w2, false) +
                   __builtin_amdgcn_cvt_pk_f32_fp8((int)w3, false);
        a01 += t0 + t1;
        t0 = __builtin_amdgcn_cvt_pk_f32_fp8((int)w0, true) +
             __builtin_amdgcn_cvt_pk_f32_fp8((int)w1, true);
        t1 = __builtin_amdgcn_cvt_pk_f32_fp8((int)w2, true) +
             __builtin_amdgcn_cvt_pk_f32_fp8((int)w3, true);
        a23 += t0 + t1;
    }
    float a[4] = {a01.x, a01.y, a23.x, a23.y};
#pragma unroll
    for (int i = 0; i < 4; i++) {
        a[i] += __shfl_xor(a[i], 16, 64);
        a[i] += __shfl_xor(a[i], 32, 64);
    }
    if (lane < 16) {
        float dv = dinv[wid];
        float sc = dv * 0.0625f;
        uint2 sp = *(const uint2*)(g16 + (size_t)wid * 64 + f * 4);
        float4 bb = *(const float4*)(bias + f * 4);
        float v0 = fmaf(a[0], sc, fmaf(bfu2f(sp.x << 16), dv, bb.x));
        float v1 = fmaf(a[1], sc, fmaf(bfu2f(sp.x & 0xffff0000u), dv, bb.y));
        float v2 = fmaf(a[2], sc, fmaf(bfu2f(sp.y << 16), dv, bb.z));
        float v3 = fmaf(a[3], sc, fmaf(bfu2f(sp.y & 0xffff0000u), dv, bb.w));
        float m = fmaxf(fmaxf(v0, v1), fmaxf(v2, v3));
#pragma unroll
        for (int d = 8; d >= 1; d >>= 1) m = fmaxf(m, __shfl_xor(m, d, 64));
        float ssum = __expf(v0 - m) + __expf(v1 - m) + __expf(v2 - m) + __expf(v3 - m);
#pragma unroll
        for (int d = 8; d >= 1; d >>= 1) ssum += __shfl_xor(ssum, d, 64);
        float lg = m + __logf(ssum);
        *(float4*)&out[(size_t)wid * 64 + f * 4] =
            make_float4(v0 - lg, v1 - lg, v2 - lg, v3 - lg);
    }
}

extern "C" void kernel_launch(void* const* d_in, const int* in_sizes, int n_in,
                              void* d_out, int out_size, void* d_ws, size_t ws_size,
                              hipStream_t stream) {
    const float* x  = (const float*)d_in[0];
    const int*   ei = (const int*)d_in[1];
    const float* W1 = (const float*)d_in[2];
    const float* b1 = (const float*)d_in[3];
    const float* W2 = (const float*)d_in[4];
    const float* b2 = (const float*)d_in[5];
    const float* W3 = (const float*)d_in[6];
    const float* b3 = (const float*)d_in[7];
    const int N = in_sizes[0] / 128;
    const int E = in_sizes[1] / 2;
    const int NBIN = (N + 127) >> 7;  // bins of 128 dsts

    char* ws = (char*)d_ws;
    size_t o = 0;
    auto alloc = [&](size_t bytes) -> char* {
        char* p = ws + o;
        o += (bytes + 255) & ~(size_t)255;
        return p;
    };
    int*   binTot = (int*)alloc((size_t)MAXBIN * 4);
    int*   binSt  = (int*)alloc((size_t)(MAXBIN + 1) * 4);
    int*   binCur = (int*)alloc((size_t)MAXBIN * 4);
    float* dinv   = (float*)alloc((size_t)N * 4);
    int*   offs   = (int*)alloc((size_t)(N + 1) * 4);
    int*   csr    = (int*)alloc((size_t)E * 4);
    u16*   wt1    = (u16*)alloc(128 * 128 * 2);
    u16*   wt2    = (u16*)alloc(128 * 128 * 2);
    u16*   wt3    = (u16*)alloc(64 * 128 * 2);
    u16*   g16    = (u16*)alloc((size_t)N * 128 * 2);
    u8*    g8     = (u8*)alloc((size_t)N * 128);
    u16*   hbuf   = (u16*)alloc((size_t)N * 128 * 2);
    u32*   binned = (u32*)g16;  // lifetime-disjoint alias: dead before first GEMM
    float* outp   = (float*)d_out;

    hipMemsetAsync(binTot, 0, (size_t)MAXBIN * 4, stream);
    int W = (E + 255) / 256;  // edge chunk per block for 256-block passes
    k_bhist<<<256, 256, 0, stream>>>(ei, E, W, binTot, NBIN);
    k_bscan<<<1, 256, 0, stream>>>(binTot, NBIN, binSt, binCur);
    k_bscatter<<<256, 256, 0, stream>>>(ei, E, W, binCur, binned, NBIN);
    k_bcsr<<<NBIN, 256, 0, stream>>>(binned, binSt, N, E, offs, dinv, csr, NBIN);
    k_wtall<<<(40960 + 255) / 256, 256, 0, stream>>>(W1, W2, W3, wt1, wt2, wt3);

    int gG = (N + 63) / 64;                       // GEMM: 64 nodes/block
    int gA = (int)(((size_t)N * 64 + 255) / 256); // agg: 1 wave/node

    k_gemm<128, true ><<<gG, 256, 0, stream>>>(x,    wt1, dinv, g16, g8, N);
    k_agg128<<<gA, 256, 0, stream>>>(g8, g16, offs, csr, dinv, b1, hbuf, N);
    k_gemm<128, false><<<gG, 256, 0, stream>>>(hbuf, wt2, dinv, g16, g8, N);
    k_agg128<<<gA, 256, 0, stream>>>(g8, g16, offs, csr, dinv, b2, hbuf, N);
    k_gemm<64,  false><<<gG, 256, 0, stream>>>(hbuf, wt3, dinv, g16, g8, N);
    k_agg64<<<gA, 256, 0, stream>>>(g8, g16, offs, csr, dinv, b3, outp, N);
}

// Round 9
// 346.570 us; speedup vs baseline: 1.0516x; 1.0347x over previous
//
#include <hip/hip_runtime.h>

typedef unsigned int u32;
typedef unsigned short u16;
typedef unsigned char u8;
typedef __attribute__((ext_vector_type(8))) short short8;
typedef __attribute__((ext_vector_type(4))) float f32x4;
typedef __attribute__((ext_vector_type(2))) float f32x2;

#define MAXBIN 1024  // bins of 128 dsts; N=100k -> 782 bins

__device__ inline float bfu2f(u32 u) { return __builtin_bit_cast(float, u); }
__device__ inline u16 f2bf(float f) {
    u32 u = __builtin_bit_cast(u32, f);
    u32 r = (u + 0x7fffu + ((u >> 16) & 1u)) >> 16;  // RTNE
    return (u16)r;
}

// ---------- CSR build: two-level binned counting sort, LDS-resident counters ----
__global__ __launch_bounds__(256) void k_bhist(const int* __restrict__ ei, int E, int W,
                                               int* __restrict__ binTot, int NBIN) {
    __shared__ int h[MAXBIN];
    int tid = threadIdx.x;
    for (int i = tid; i < NBIN; i += 256) h[i] = 0;
    __syncthreads();
    int s = blockIdx.x * W, e = min(E, s + W);
    for (int j = s + tid; j < e; j += 256) atomicAdd(&h[ei[E + j] >> 7], 1);
    __syncthreads();
    for (int i = tid; i < NBIN; i += 256) {
        int v = h[i];
        if (v) atomicAdd(&binTot[i], v);
    }
}

__global__ void k_bscan(const int* __restrict__ binTot, int NBIN,
                        int* __restrict__ binStart, int* __restrict__ binCur) {
    __shared__ int wsum[4];
    int t = threadIdx.x;
    int base = t * 4;
    int v0 = (base + 0 < NBIN) ? binTot[base + 0] : 0;
    int v1 = (base + 1 < NBIN) ? binTot[base + 1] : 0;
    int v2 = (base + 2 < NBIN) ? binTot[base + 2] : 0;
    int v3 = (base + 3 < NBIN) ? binTot[base + 3] : 0;
    int s = v0 + v1 + v2 + v3;
    int lane = t & 63, wv = t >> 6;
    int isc = s;
    for (int d = 1; d < 64; d <<= 1) { int o = __shfl_up(isc, d, 64); if (lane >= d) isc += o; }
    if (lane == 63) wsum[wv] = isc;
    __syncthreads();
    int woff = 0;
    for (int w = 0; w < wv; w++) woff += wsum[w];
    int run = woff + isc - s;
    if (base + 0 < NBIN) { binStart[base + 0] = run; binCur[base + 0] = run; } run += v0;
    if (base + 1 < NBIN) { binStart[base + 1] = run; binCur[base + 1] = run; } run += v1;
    if (base + 2 < NBIN) { binStart[base + 2] = run; binCur[base + 2] = run; } run += v2;
    if (base + 3 < NBIN) { binStart[base + 3] = run; binCur[base + 3] = run; }
    if (t == 255) binStart[NBIN] = wsum[0] + wsum[1] + wsum[2] + wsum[3];
}

__global__ __launch_bounds__(256) void k_bscatter(const int* __restrict__ ei, int E, int W,
                                                  int* __restrict__ binCur,
                                                  u32* __restrict__ binned, int NBIN) {
    __shared__ int lh[MAXBIN];
    __shared__ int lb[MAXBIN];
    int tid = threadIdx.x;
    for (int i = tid; i < NBIN; i += 256) lh[i] = 0;
    __syncthreads();
    int s = blockIdx.x * W, e = min(E, s + W);
    for (int j = s + tid; j < e; j += 256) atomicAdd(&lh[ei[E + j] >> 7], 1);
    __syncthreads();
    for (int i = tid; i < NBIN; i += 256) {
        int h = lh[i];
        lb[i] = h ? atomicAdd(&binCur[i], h) : 0;
    }
    __syncthreads();
    for (int i = tid; i < NBIN; i += 256) lh[i] = 0;
    __syncthreads();
    for (int j = s + tid; j < e; j += 256) {
        int d = ei[E + j];
        int b = d >> 7;
        int r = atomicAdd(&lh[b], 1);
        binned[lb[b] + r] = ((u32)ei[j] << 7) | (u32)(d & 127);
    }
}

__global__ __launch_bounds__(256) void k_bcsr(const u32* __restrict__ binned,
                                              const int* __restrict__ binStart,
                                              int N, int E, int* __restrict__ offs,
                                              float* __restrict__ dinv,
                                              int* __restrict__ csr, int NBIN) {
    __shared__ int cnt[128];
    __shared__ int off[128];
    __shared__ int tot;
    int b = blockIdx.x;
    int tid = threadIdx.x;
    int dLo = b << 7;
    int nd = min(128, N - dLo);
    int e0 = binStart[b], e1 = binStart[b + 1];
    if (tid < 128) cnt[tid] = 0;
    __syncthreads();
    for (int j = e0 + tid; j < e1; j += 256) atomicAdd(&cnt[binned[j] & 127u], 1);
    __syncthreads();
    int c = (tid < 128) ? cnt[tid] : 0;
    int lane = tid & 63;
    int isc = c;
    for (int d = 1; d < 64; d <<= 1) { int o = __shfl_up(isc, d, 64); if (lane >= d) isc += o; }
    if (tid == 63) tot = isc;
    __syncthreads();
    int add = (tid >= 64 && tid < 128) ? tot : 0;
    if (tid < 128) off[tid] = add + isc - c;
    __syncthreads();
    if (tid < nd) {
        offs[dLo + tid] = e0 + off[tid];
        dinv[dLo + tid] = rsqrtf((float)(c + 1));
    }
    if (b == NBIN - 1 && tid == 0) offs[N] = E;
    if (tid < 128) cnt[tid] = 0;
    __syncthreads();
    for (int j = e0 + tid; j < e1; j += 256) {
        u32 v = binned[j];
        int d7 = (int)(v & 127u);
        int r = atomicAdd(&cnt[d7], 1);
        csr[e0 + off[d7] + r] = (int)(v >> 7);
    }
}

// ---------- fused weight converts (W[K][M] row-major -> Wt[M][K] bf16) ----------
__global__ void k_wtall(const float* __restrict__ W1, const float* __restrict__ W2,
                        const float* __restrict__ W3, u16* __restrict__ wt1,
                        u16* __restrict__ wt2, u16* __restrict__ wt3) {
    int idx = blockIdx.x * 256 + threadIdx.x;
    if (idx < 16384) {
        int k = idx >> 7, m = idx & 127;
        wt1[m * 128 + k] = f2bf(W1[idx]);
    } else if (idx < 32768) {
        int i = idx - 16384, k = i >> 7, m = i & 127;
        wt2[m * 128 + k] = f2bf(W2[i]);
    } else if (idx < 40960) {
        int i = idx - 32768, k = i >> 6, m = i & 63;
        wt3[m * 128 + k] = f2bf(W3[i]);
    }
}

// ---------- GEMM: g8 = fp8((x @ W) * dinv[row] * 16)  (fp8 only; self read from g8) --
template <int M, bool F32IN>
__global__ __launch_bounds__(256) void k_gemm(const void* __restrict__ xin,
                                              const u16* __restrict__ wt,
                                              const float* __restrict__ dinv,
                                              u8* __restrict__ g8, int N) {
    constexpr int K = 128;
    constexpr int LDK = 136;
    __shared__ u16 lwt[M * LDK];
    int tid = threadIdx.x;
    const uint4* wsrc = (const uint4*)wt;
#pragma unroll
    for (int c = tid; c < M * K / 8; c += 256) {
        int row = c >> 4, kc = c & 15;
        *(uint4*)&lwt[row * LDK + kc * 8] = wsrc[c];
    }
    __syncthreads();
    int lane = tid & 63, wv = tid >> 6;
    int node = blockIdx.x * 64 + wv * 16 + (lane & 15);
    int nodec = min(node, N - 1);
    int kr = (lane >> 4) * 8;
    f32x4 acc[M / 16];
#pragma unroll
    for (int t = 0; t < M / 16; t++) acc[t] = (f32x4){0.f, 0.f, 0.f, 0.f};
#pragma unroll
    for (int ks = 0; ks < 4; ks++) {
        short8 bfr;
        if (F32IN) {
            const float* xr = (const float*)xin + (size_t)nodec * K + ks * 32 + kr;
            float4 fa = *(const float4*)xr;
            float4 fb = *(const float4*)(xr + 4);
            bfr = (short8){(short)f2bf(fa.x), (short)f2bf(fa.y), (short)f2bf(fa.z),
                           (short)f2bf(fa.w), (short)f2bf(fb.x), (short)f2bf(fb.y),
                           (short)f2bf(fb.z), (short)f2bf(fb.w)};
        } else {
            bfr = *(const short8*)((const u16*)xin + (size_t)nodec * K + ks * 32 + kr);
        }
#pragma unroll
        for (int t = 0; t < M / 16; t++) {
            short8 afr = *(const short8*)&lwt[(t * 16 + (lane & 15)) * LDK + ks * 32 + kr];
            acc[t] = __builtin_amdgcn_mfma_f32_16x16x32_bf16(afr, bfr, acc[t], 0, 0, 0);
        }
    }
    if (node < N) {
        float dv16 = dinv[node] * 16.0f;
        int r0 = (lane >> 4) * 4;
#pragma unroll
        for (int t = 0; t < M / 16; t++) {
            u32 w = __builtin_amdgcn_cvt_pk_fp8_f32(acc[t][0] * dv16, acc[t][1] * dv16, 0, false);
            w = __builtin_amdgcn_cvt_pk_fp8_f32(acc[t][2] * dv16, acc[t][3] * dv16, w, true);
            *(u32*)(g8 + (size_t)node * M + t * 16 + r0) = w;
        }
    }
}

// ---------- aggregation: 16 edges/iter, 4 gathers in flight, fully masked ----------
// quarter q handles edges j+4q..j+4q+3; lane covers 8 features via uint2 fp8.
// self-loop also fp8 (g16 buffer eliminated: agg is at its compulsory-fetch floor,
// so the lever is bytes -- R8 A/B showed MLP doesn't move it).
__global__ __launch_bounds__(256) void k_agg128(const u8* __restrict__ g8,
                                                const int* __restrict__ offs,
                                                const int* __restrict__ csr,
                                                const float* __restrict__ dinv,
                                                const float* __restrict__ bias,
                                                u16* __restrict__ hout, int N) {
    int wid = (blockIdx.x * 256 + threadIdx.x) >> 6;  // one wave per node
    if (wid >= N) return;
    int lane = threadIdx.x & 63;
    int q = lane >> 4;
    int f = lane & 15;
    int s = offs[wid], e = offs[wid + 1];
    const u8* gf = g8 + f * 8;  // u32 row offsets -> saddr addressing
    f32x2 a01 = {0.f, 0.f}, a23 = {0.f, 0.f}, a45 = {0.f, 0.f}, a67 = {0.f, 0.f};
    int em1 = e - 1;
    for (int j = s; j < e; j += 16) {
        int b4 = j + q * 4;
        int i1 = b4 + 1, i2 = b4 + 2, i3 = b4 + 3;
        int s0 = csr[min(b4, em1)];
        int s1 = csr[min(i1, em1)];
        int s2 = csr[min(i2, em1)];
        int s3 = csr[min(i3, em1)];
        uint2 w0 = *(const uint2*)(gf + ((u32)s0 << 7));
        uint2 w1 = *(const uint2*)(gf + ((u32)s1 << 7));
        uint2 w2 = *(const uint2*)(gf + ((u32)s2 << 7));
        uint2 w3 = *(const uint2*)(gf + ((u32)s3 << 7));
        if (b4 >= e) { w0.x = 0u; w0.y = 0u; }  // fp8 0x00 == 0.0
        if (i1 >= e) { w1.x = 0u; w1.y = 0u; }
        if (i2 >= e) { w2.x = 0u; w2.y = 0u; }
        if (i3 >= e) { w3.x = 0u; w3.y = 0u; }
        f32x2 t0, t1;
        t0 = __builtin_amdgcn_cvt_pk_f32_fp8((int)w0.x, false) +
             __builtin_amdgcn_cvt_pk_f32_fp8((int)w1.x, false);
        t1 = __builtin_amdgcn_cvt_pk_f32_fp8((int)w2.x, false) +
             __builtin_amdgcn_cvt_pk_f32_fp8((int)w3.x, false);
        a01 += t0 + t1;
        t0 = __builtin_amdgcn_cvt_pk_f32_fp8((int)w0.x, true) +
             __builtin_amdgcn_cvt_pk_f32_fp8((int)w1.x, true);
        t1 = __builtin_amdgcn_cvt_pk_f32_fp8((int)w2.x, true) +
             __builtin_amdgcn_cvt_pk_f32_fp8((int)w3.x, true);
        a23 += t0 + t1;
        t0 = __builtin_amdgcn_cvt_pk_f32_fp8((int)w0.y, false) +
             __builtin_amdgcn_cvt_pk_f32_fp8((int)w1.y, false);
        t1 = __builtin_amdgcn_cvt_pk_f32_fp8((int)w2.y, false) +
             __builtin_amdgcn_cvt_pk_f32_fp8((int)w3.y, false);
        a45 += t0 + t1;
        t0 = __builtin_amdgcn_cvt_pk_f32_fp8((int)w0.y, true) +
             __builtin_amdgcn_cvt_pk_f32_fp8((int)w1.y, true);
        t1 = __builtin_amdgcn_cvt_pk_f32_fp8((int)w2.y, true) +
             __builtin_amdgcn_cvt_pk_f32_fp8((int)w3.y, true);
        a67 += t0 + t1;
    }
    float a[8] = {a01.x, a01.y, a23.x, a23.y, a45.x, a45.y, a67.x, a67.y};
#pragma unroll
    for (int i = 0; i < 8; i++) {
        a[i] += __shfl_xor(a[i], 16, 64);
        a[i] += __shfl_xor(a[i], 32, 64);
    }
    if (lane < 16) {
        float sc = dinv[wid] * 0.0625f;
        uint2 sp = *(const uint2*)(g8 + (size_t)wid * 128 + f * 8);  // self, fp8 x8
        f32x2 s01 = __builtin_amdgcn_cvt_pk_f32_fp8((int)sp.x, false);
        f32x2 s23 = __builtin_amdgcn_cvt_pk_f32_fp8((int)sp.x, true);
        f32x2 s45 = __builtin_amdgcn_cvt_pk_f32_fp8((int)sp.y, false);
        f32x2 s67 = __builtin_amdgcn_cvt_pk_f32_fp8((int)sp.y, true);
        float sv[8] = {s01.x, s01.y, s23.x, s23.y, s45.x, s45.y, s67.x, s67.y};
        float4 b0 = *(const float4*)(bias + f * 8);
        float4 b1 = *(const float4*)(bias + f * 8 + 4);
        float bv[8] = {b0.x, b0.y, b0.z, b0.w, b1.x, b1.y, b1.z, b1.w};
        u32 o[4];
#pragma unroll
        for (int i = 0; i < 4; i++) {
            float v0 = fmaxf(fmaf(a[2 * i] + sv[2 * i], sc, bv[2 * i]), 0.f);
            float v1 = fmaxf(fmaf(a[2 * i + 1] + sv[2 * i + 1], sc, bv[2 * i + 1]), 0.f);
            o[i] = (u32)f2bf(v0) | ((u32)f2bf(v1) << 16);
        }
        *(uint4*)&hout[(size_t)wid * 128 + f * 8] = make_uint4(o[0], o[1], o[2], o[3]);
    }
}

// ---------- layer-3 aggregation + log_softmax (F=64, fp32 out) ----------
__global__ __launch_bounds__(256) void k_agg64(const u8* __restrict__ g8,
                                               const int* __restrict__ offs,
                                               const int* __restrict__ csr,
                                               const float* __restrict__ dinv,
                                               const float* __restrict__ bias,
                                               float* __restrict__ out, int N) {
    int wid = (blockIdx.x * 256 + threadIdx.x) >> 6;
    if (wid >= N) return;
    int lane = threadIdx.x & 63;
    int q = lane >> 4;
    int f = lane & 15;
    int s = offs[wid], e = offs[wid + 1];
    const u8* gf = g8 + f * 4;
    f32x2 a01 = {0.f, 0.f}, a23 = {0.f, 0.f};
    int em1 = e - 1;
    for (int j = s; j < e; j += 16) {
        int b4 = j + q * 4;
        int i1 = b4 + 1, i2 = b4 + 2, i3 = b4 + 3;
        int s0 = csr[min(b4, em1)];
        int s1 = csr[min(i1, em1)];
        int s2 = csr[min(i2, em1)];
        int s3 = csr[min(i3, em1)];
        u32 w0 = *(const u32*)(gf + ((u32)s0 << 6));
        u32 w1 = *(const u32*)(gf + ((u32)s1 << 6));
        u32 w2 = *(const u32*)(gf + ((u32)s2 << 6));
        u32 w3 = *(const u32*)(gf + ((u32)s3 << 6));
        if (b4 >= e) w0 = 0u;
        if (i1 >= e) w1 = 0u;
        if (i2 >= e) w2 = 0u;
        if (i3 >= e) w3 = 0u;
        f32x2 t0 = __builtin_amdgcn_cvt_pk_f32_fp8((int)w0, false) +
                   __builtin_amdgcn_cvt_pk_f32_fp8((int)w1, false);
        f32x2 t1 = __builtin_amdgcn_cvt_pk_f32_fp8((int)w2, false) +
                   __builtin_amdgcn_cvt_pk_f32_fp8((int)w3, false);
        a01 += t0 + t1;
        t0 = __builtin_amdgcn_cvt_pk_f32_fp8((int)w0, true) +
             __builtin_amdgcn_cvt_pk_f32_fp8((int)w1, true);
        t1 = __builtin_amdgcn_cvt_pk_f32_fp8((int)w2, true) +
             __builtin_amdgcn_cvt_pk_f32_fp8((int)w3, true);
        a23 += t0 + t1;
    }
    float a[4] = {a01.x, a01.y, a23.x, a23.y};
#pragma unroll
    for (int i = 0; i < 4; i++) {
        a[i] += __shfl_xor(a[i], 16, 64);
        a[i] += __shfl_xor(a[i], 32, 64);
    }
    if (lane < 16) {
        float sc = dinv[wid] * 0.0625f;
        u32 sp = *(const u32*)(g8 + (size_t)wid * 64 + f * 4);  // self, fp8 x4
        f32x2 s01 = __builtin_amdgcn_cvt_pk_f32_fp8((int)sp, false);
        f32x2 s23 = __builtin_amdgcn_cvt_pk_f32_fp8((int)sp, true);
        float4 bb = *(const float4*)(bias + f * 4);
        float v0 = fmaf(a[0] + s01.x, sc, bb.x);
        float v1 = fmaf(a[1] + s01.y, sc, bb.y);
        float v2 = fmaf(a[2] + s23.x, sc, bb.z);
        float v3 = fmaf(a[3] + s23.y, sc, bb.w);
        float m = fmaxf(fmaxf(v0, v1), fmaxf(v2, v3));
#pragma unroll
        for (int d = 8; d >= 1; d >>= 1) m = fmaxf(m, __shfl_xor(m, d, 64));
        float ssum = __expf(v0 - m) + __expf(v1 - m) + __expf(v2 - m) + __expf(v3 - m);
#pragma unroll
        for (int d = 8; d >= 1; d >>= 1) ssum += __shfl_xor(ssum, d, 64);
        float lg = m + __logf(ssum);
        *(float4*)&out[(size_t)wid * 64 + f * 4] =
            make_float4(v0 - lg, v1 - lg, v2 - lg, v3 - lg);
    }
}

extern "C" void kernel_launch(void* const* d_in, const int* in_sizes, int n_in,
                              void* d_out, int out_size, void* d_ws, size_t ws_size,
                              hipStream_t stream) {
    const float* x  = (const float*)d_in[0];
    const int*   ei = (const int*)d_in[1];
    const float* W1 = (const float*)d_in[2];
    const float* b1 = (const float*)d_in[3];
    const float* W2 = (const float*)d_in[4];
    const float* b2 = (const float*)d_in[5];
    const float* W3 = (const float*)d_in[6];
    const float* b3 = (const float*)d_in[7];
    const int N = in_sizes[0] / 128;
    const int E = in_sizes[1] / 2;
    const int NBIN = (N + 127) >> 7;  // bins of 128 dsts

    char* ws = (char*)d_ws;
    size_t o = 0;
    auto alloc = [&](size_t bytes) -> char* {
        char* p = ws + o;
        o += (bytes + 255) & ~(size_t)255;
        return p;
    };
    int*   binTot = (int*)alloc((size_t)MAXBIN * 4);
    int*   binSt  = (int*)alloc((size_t)(MAXBIN + 1) * 4);
    int*   binCur = (int*)alloc((size_t)MAXBIN * 4);
    float* dinv   = (float*)alloc((size_t)N * 4);
    int*   offs   = (int*)alloc((size_t)(N + 1) * 4);
    int*   csr    = (int*)alloc((size_t)E * 4);
    u16*   wt1    = (u16*)alloc(128 * 128 * 2);
    u16*   wt2    = (u16*)alloc(128 * 128 * 2);
    u16*   wt3    = (u16*)alloc(64 * 128 * 2);
    u8*    g8     = (u8*)alloc((size_t)N * 128);
    u16*   hbuf   = (u16*)alloc((size_t)N * 128 * 2);
    u32*   binned = (u32*)hbuf;  // lifetime-disjoint alias: dead before first agg write
    float* outp   = (float*)d_out;

    hipMemsetAsync(binTot, 0, (size_t)MAXBIN * 4, stream);
    int W256 = (E + 255) / 256;
    int W128 = (E + 127) / 128;
    k_bhist<<<256, 256, 0, stream>>>(ei, E, W256, binTot, NBIN);
    k_bscan<<<1, 256, 0, stream>>>(binTot, NBIN, binSt, binCur);
    k_bscatter<<<128, 256, 0, stream>>>(ei, E, W128, binCur, binned, NBIN);
    k_bcsr<<<NBIN, 256, 0, stream>>>(binned, binSt, N, E, offs, dinv, csr, NBIN);
    k_wtall<<<(40960 + 255) / 256, 256, 0, stream>>>(W1, W2, W3, wt1, wt2, wt3);

    int gG = (N + 63) / 64;                       // GEMM: 64 nodes/block
    int gA = (int)(((size_t)N * 64 + 255) / 256); // agg: 1 wave/node

    k_gemm<128, true ><<<gG, 256, 0, stream>>>(x,    wt1, dinv, g8, N);
    k_agg128<<<gA, 256, 0, stream>>>(g8, offs, csr, dinv, b1, hbuf, N);
    k_gemm<128, false><<<gG, 256, 0, stream>>>(hbuf, wt2, dinv, g8, N);
    k_agg128<<<gA, 256, 0, stream>>>(g8, offs, csr, dinv, b2, hbuf, N);
    k_gemm<64,  false><<<gG, 256, 0, stream>>>(hbuf, wt3, dinv, g8, N);
    k_agg64<<<gA, 256, 0, stream>>>(g8, offs, csr, dinv, b3, outp, N);
}